// Round 1
// baseline (6888.812 us; speedup 1.0000x reference)
//
#include <hip/hip_runtime.h>
#include <hip/hip_bf16.h>
#include <math.h>

#define TPB 256

// ---------------------------------------------------------------------------
// Stage 1: per-point edge MLP + attention gate, scatter-add into agg[C][64].
// Weights are read directly from global with compile-time-constant indices:
// addresses are wave-uniform -> compiler emits scalar loads (s_load) and
// SGPR-operand v_fmac. No LDS staging needed.
// ---------------------------------------------------------------------------
__global__ __launch_bounds__(TPB) void point_kernel(
    const float* __restrict__ pf, const int* __restrict__ labels,
    const float* __restrict__ centers, const float* __restrict__ points,
    const float* __restrict__ we0, const float* __restrict__ be0,
    const float* __restrict__ we1, const float* __restrict__ be1,
    const float* __restrict__ we2, const float* __restrict__ be2,
    const float* __restrict__ we3, const float* __restrict__ be3,
    const float* __restrict__ wa0, const float* __restrict__ ba0,
    const float* __restrict__ wa1, const float* __restrict__ ba1,
    float* __restrict__ agg, int n)
{
    int i = blockIdx.x * TPB + threadIdx.x;
    if (i >= n) return;

    float x[11];
    const float4* pf4 = (const float4*)pf;
    float4 p0 = pf4[(size_t)i * 2 + 0];
    float4 p1 = pf4[(size_t)i * 2 + 1];
    x[0] = p0.x; x[1] = p0.y; x[2] = p0.z; x[3] = p0.w;
    x[4] = p1.x; x[5] = p1.y; x[6] = p1.z; x[7] = p1.w;

    int lbl = labels[i];
    x[8]  = centers[lbl * 3 + 0] - points[(size_t)i * 3 + 0];
    x[9]  = centers[lbl * 3 + 1] - points[(size_t)i * 3 + 1];
    x[10] = centers[lbl * 3 + 2] - points[(size_t)i * 3 + 2];

    // ---- attention MLP: 11 -> 64 (relu) -> 1 (sigmoid), computed scalar ----
    float s = ba1[0];
#pragma unroll
    for (int j = 0; j < 64; j++) {
        float aj = ba0[j];
#pragma unroll
        for (int k = 0; k < 11; k++) aj = fmaf(x[k], wa0[k * 64 + j], aj);
        aj = fmaxf(aj, 0.f);
        s = fmaf(aj, wa1[j], s);
    }
    float gate = 1.f / (1.f + __expf(-s));

    // ---- edge MLP: 11 -> 8 -> 16 -> 32 -> 64, relu each ----
    float h1[8];
#pragma unroll
    for (int j = 0; j < 8; j++) {
        float v = be0[j];
#pragma unroll
        for (int k = 0; k < 11; k++) v = fmaf(x[k], we0[k * 8 + j], v);
        h1[j] = fmaxf(v, 0.f);
    }
    float h2[16];
#pragma unroll
    for (int j = 0; j < 16; j++) {
        float v = be1[j];
#pragma unroll
        for (int k = 0; k < 8; k++) v = fmaf(h1[k], we1[k * 16 + j], v);
        h2[j] = fmaxf(v, 0.f);
    }
    float h3[32];
#pragma unroll
    for (int j = 0; j < 32; j++) {
        float v = be2[j];
#pragma unroll
        for (int k = 0; k < 16; k++) v = fmaf(h2[k], we2[k * 32 + j], v);
        h3[j] = fmaxf(v, 0.f);
    }

    size_t base = (size_t)lbl * 64;
#pragma unroll
    for (int j = 0; j < 64; j++) {
        float v = be3[j];
#pragma unroll
        for (int k = 0; k < 32; k++) v = fmaf(h3[k], we3[k * 64 + j], v);
        v = fmaxf(v, 0.f);
        atomicAdd(&agg[base + j], v * gate);
    }
}

// ---------------------------------------------------------------------------
// Stage 2: per-cluster output MLP  agg[C][64] -> relu(@wo0+bo0)[128]
//          -> relu(@wo1+bo1)[256].  64 clusters per block, 256 threads.
// Register-tiled over clusters so each wo1 element is read once per block
// (coalesced across lanes), keeping L2 weight traffic ~0.5 GB total.
// ---------------------------------------------------------------------------
__global__ __launch_bounds__(TPB) void out_mlp_kernel(
    const float* __restrict__ agg,
    const float* __restrict__ wo0, const float* __restrict__ bo0,
    const float* __restrict__ wo1, const float* __restrict__ bo1,
    float* __restrict__ out)
{
    __shared__ float s_agg[64 * 64];    // 16 KB
    __shared__ float s_mid[64 * 128];   // 32 KB
    int tid = threadIdx.x;
    int c0 = blockIdx.x * 64;

    // phase 1: stage agg tile (64 clusters x 64 feats) into LDS
    {
        const float4* gsrc = (const float4*)(agg + (size_t)c0 * 64);
        float4* ldst = (float4*)s_agg;
#pragma unroll
        for (int i = 0; i < 4; i++) ldst[tid + i * 256] = gsrc[tid + i * 256];
    }
    __syncthreads();

    // phase 2: mid[64][128] = relu(agg @ wo0 + bo0)
    {
        int j = tid & 127;
        int chalf = tid >> 7;   // 0 or 1: which 32-cluster half
        float acc[32];
        float b = bo0[j];
#pragma unroll
        for (int c = 0; c < 32; c++) acc[c] = b;
        for (int k = 0; k < 64; k += 4) {
            float w0 = wo0[(k + 0) * 128 + j];
            float w1 = wo0[(k + 1) * 128 + j];
            float w2 = wo0[(k + 2) * 128 + j];
            float w3 = wo0[(k + 3) * 128 + j];
#pragma unroll
            for (int c = 0; c < 32; c++) {
                // broadcast LDS read (same address across the wave)
                const float4 av = *(const float4*)&s_agg[(chalf * 32 + c) * 64 + k];
                acc[c] = fmaf(av.x, w0, acc[c]);
                acc[c] = fmaf(av.y, w1, acc[c]);
                acc[c] = fmaf(av.z, w2, acc[c]);
                acc[c] = fmaf(av.w, w3, acc[c]);
            }
        }
#pragma unroll
        for (int c = 0; c < 32; c++)
            s_mid[(chalf * 32 + c) * 128 + j] = fmaxf(acc[c], 0.f);
    }
    __syncthreads();

    // phase 3: out[64][256] = relu(mid @ wo1 + bo1)
    {
        int m = tid;  // 0..255
        float acc[64];
        float b = bo1[m];
#pragma unroll
        for (int c = 0; c < 64; c++) acc[c] = b;
        for (int j = 0; j < 128; j += 4) {
            float w0 = wo1[(j + 0) * 256 + m];
            float w1 = wo1[(j + 1) * 256 + m];
            float w2 = wo1[(j + 2) * 256 + m];
            float w3 = wo1[(j + 3) * 256 + m];
#pragma unroll
            for (int c = 0; c < 64; c++) {
                const float4 mv = *(const float4*)&s_mid[c * 128 + j];
                acc[c] = fmaf(mv.x, w0, acc[c]);
                acc[c] = fmaf(mv.y, w1, acc[c]);
                acc[c] = fmaf(mv.z, w2, acc[c]);
                acc[c] = fmaf(mv.w, w3, acc[c]);
            }
        }
#pragma unroll
        for (int c = 0; c < 64; c++)
            out[(size_t)(c0 + c) * 256 + m] = fmaxf(acc[c], 0.f);
    }
}

extern "C" void kernel_launch(void* const* d_in, const int* in_sizes, int n_in,
                              void* d_out, int out_size, void* d_ws, size_t ws_size,
                              hipStream_t stream)
{
    const float* pf      = (const float*)d_in[0];
    const int*   labels  = (const int*)d_in[1];
    const float* centers = (const float*)d_in[2];
    const float* points  = (const float*)d_in[3];
    const float* we0 = (const float*)d_in[4];
    const float* be0 = (const float*)d_in[5];
    const float* we1 = (const float*)d_in[6];
    const float* be1 = (const float*)d_in[7];
    const float* we2 = (const float*)d_in[8];
    const float* be2 = (const float*)d_in[9];
    const float* we3 = (const float*)d_in[10];
    const float* be3 = (const float*)d_in[11];
    const float* wa0 = (const float*)d_in[12];
    const float* ba0 = (const float*)d_in[13];
    const float* wa1 = (const float*)d_in[14];
    const float* ba1 = (const float*)d_in[15];
    const float* wo0 = (const float*)d_in[16];
    const float* bo0 = (const float*)d_in[17];
    const float* wo1 = (const float*)d_in[18];
    const float* bo1 = (const float*)d_in[19];
    float* out = (float*)d_out;

    int n = in_sizes[0] / 8;        // N points
    int C = in_sizes[2] / 3;        // cluster count

    float* agg = (float*)d_ws;      // C x 64 f32 accumulator (16.8 MB)
    hipMemsetAsync(agg, 0, (size_t)C * 64 * sizeof(float), stream);

    point_kernel<<<(n + TPB - 1) / TPB, TPB, 0, stream>>>(
        pf, labels, centers, points,
        we0, be0, we1, be1, we2, be2, we3, be3,
        wa0, ba0, wa1, ba1, agg, n);

    out_mlp_kernel<<<C / 64, TPB, 0, stream>>>(agg, wo0, bo0, wo1, bo1, out);
}

// Round 2
// 4486.151 us; speedup vs baseline: 1.5356x; 1.5356x over previous
//
#include <hip/hip_runtime.h>
#include <hip/hip_bf16.h>
#include <math.h>

#define TPB 256
#define NC 64   // clusters per compute block

// ---------------------------------------------------------------------------
// Sort stage 1: histogram of labels
// ---------------------------------------------------------------------------
__global__ __launch_bounds__(TPB) void hist_kernel(
    const int* __restrict__ labels, int* __restrict__ counts, int n)
{
    int i = blockIdx.x * TPB + threadIdx.x;
    if (i < n) atomicAdd(&counts[labels[i]], 1);
}

// ---------------------------------------------------------------------------
// Sort stage 2: exclusive prefix sum over C bins (single block, 1024 thr).
// Writes off[0..C] and initializes cursor[0..C-1] = off[c].
// ---------------------------------------------------------------------------
__global__ __launch_bounds__(1024) void scan_kernel(
    const int* __restrict__ counts, int* __restrict__ off,
    int* __restrict__ cursor, int C)
{
    __shared__ int part[1024];
    int t = threadIdx.x;
    int per = C / 1024;             // 64 bins per thread
    int b0 = t * per;
    int s = 0;
    for (int k = 0; k < per; k++) s += counts[b0 + k];
    part[t] = s;
    __syncthreads();
    // Hillis-Steele inclusive scan
    for (int d = 1; d < 1024; d <<= 1) {
        int v = 0;
        if (t >= d) v = part[t - d];
        __syncthreads();
        if (t >= d) part[t] += v;
        __syncthreads();
    }
    int run = part[t] - s;          // exclusive base for this thread's bins
    for (int k = 0; k < per; k++) {
        off[b0 + k] = run;
        cursor[b0 + k] = run;
        run += counts[b0 + k];
    }
    if (t == 1023) off[C] = run;    // == n
}

// ---------------------------------------------------------------------------
// Sort stage 3: scatter point ids into cluster-sorted order
// ---------------------------------------------------------------------------
__global__ __launch_bounds__(TPB) void scatter_kernel(
    const int* __restrict__ labels, int* __restrict__ cursor,
    int* __restrict__ sorted, int n)
{
    int i = blockIdx.x * TPB + threadIdx.x;
    if (i < n) {
        int pos = atomicAdd(&cursor[labels[i]], 1);
        sorted[pos] = i;
    }
}

// ---------------------------------------------------------------------------
// Stage 1 compute: per-point edge MLP + attention gate, accumulate into an
// LDS tile for NC clusters (no global atomics). s_agg stride 65 breaks the
// all-lanes-one-bank pattern of stride 64.
// ---------------------------------------------------------------------------
__global__ __launch_bounds__(TPB) void point_compute_kernel(
    const float* __restrict__ pf, const int* __restrict__ labels,
    const float* __restrict__ centers, const float* __restrict__ points,
    const float* __restrict__ we0, const float* __restrict__ be0,
    const float* __restrict__ we1, const float* __restrict__ be1,
    const float* __restrict__ we2, const float* __restrict__ be2,
    const float* __restrict__ we3, const float* __restrict__ be3,
    const float* __restrict__ wa0, const float* __restrict__ ba0,
    const float* __restrict__ wa1, const float* __restrict__ ba1,
    const int* __restrict__ off, const int* __restrict__ sorted,
    float* __restrict__ agg)
{
    __shared__ float s_agg[NC * 65];   // 16.6 KB
    int tid = threadIdx.x;
    int c0 = blockIdx.x * NC;

    for (int k = tid; k < NC * 65; k += TPB) s_agg[k] = 0.f;
    __syncthreads();

    int pbegin = off[c0];
    int pend   = off[c0 + NC];
    int total  = pend - pbegin;
    int per    = (total + TPB - 1) / TPB;   // contiguous chunk per thread (~8)
    int ps = pbegin + tid * per;
    int pe = ps + per; if (pe > pend) pe = pend;

    for (int p = ps; p < pe; p++) {
        int i = sorted[p];
        int lbl = labels[i];

        float x[11];
        const float4* pf4 = (const float4*)pf;
        float4 p0 = pf4[(size_t)i * 2 + 0];
        float4 p1 = pf4[(size_t)i * 2 + 1];
        x[0] = p0.x; x[1] = p0.y; x[2] = p0.z; x[3] = p0.w;
        x[4] = p1.x; x[5] = p1.y; x[6] = p1.z; x[7] = p1.w;
        x[8]  = centers[lbl * 3 + 0] - points[(size_t)i * 3 + 0];
        x[9]  = centers[lbl * 3 + 1] - points[(size_t)i * 3 + 1];
        x[10] = centers[lbl * 3 + 2] - points[(size_t)i * 3 + 2];

        // attention MLP: 11 -> 64 relu -> 1 sigmoid
        float s = ba1[0];
#pragma unroll
        for (int j = 0; j < 64; j++) {
            float aj = ba0[j];
#pragma unroll
            for (int k = 0; k < 11; k++) aj = fmaf(x[k], wa0[k * 64 + j], aj);
            aj = fmaxf(aj, 0.f);
            s = fmaf(aj, wa1[j], s);
        }
        float gate = 1.f / (1.f + __expf(-s));

        // edge MLP: 11 -> 8 -> 16 -> 32
        float h1[8];
#pragma unroll
        for (int j = 0; j < 8; j++) {
            float v = be0[j];
#pragma unroll
            for (int k = 0; k < 11; k++) v = fmaf(x[k], we0[k * 8 + j], v);
            h1[j] = fmaxf(v, 0.f);
        }
        float h2[16];
#pragma unroll
        for (int j = 0; j < 16; j++) {
            float v = be1[j];
#pragma unroll
            for (int k = 0; k < 8; k++) v = fmaf(h1[k], we1[k * 16 + j], v);
            h2[j] = fmaxf(v, 0.f);
        }
        float h3[32];
#pragma unroll
        for (int j = 0; j < 32; j++) {
            float v = be2[j];
#pragma unroll
            for (int k = 0; k < 16; k++) v = fmaf(h2[k], we2[k * 32 + j], v);
            h3[j] = fmaxf(v, 0.f);
        }

        // final layer 32 -> 64, gate, LDS accumulate
        float* dst = &s_agg[(lbl - c0) * 65];
#pragma unroll
        for (int j = 0; j < 64; j++) {
            float v = be3[j];
#pragma unroll
            for (int k = 0; k < 32; k++) v = fmaf(h3[k], we3[k * 64 + j], v);
            v = fmaxf(v, 0.f);
            atomicAdd(&dst[j], v * gate);
        }
    }
    __syncthreads();

    // write tile to global agg[C][64]
    for (int k = tid; k < NC * 64; k += TPB) {
        int lc = k >> 6, j = k & 63;
        agg[(size_t)c0 * 64 + k] = s_agg[lc * 65 + j];
    }
}

// ---------------------------------------------------------------------------
// Stage 2: per-cluster output MLP (unchanged from round 1)
// ---------------------------------------------------------------------------
__global__ __launch_bounds__(TPB) void out_mlp_kernel(
    const float* __restrict__ agg,
    const float* __restrict__ wo0, const float* __restrict__ bo0,
    const float* __restrict__ wo1, const float* __restrict__ bo1,
    float* __restrict__ out)
{
    __shared__ float s_agg[64 * 64];    // 16 KB
    __shared__ float s_mid[64 * 128];   // 32 KB
    int tid = threadIdx.x;
    int c0 = blockIdx.x * 64;

    {
        const float4* gsrc = (const float4*)(agg + (size_t)c0 * 64);
        float4* ldst = (float4*)s_agg;
#pragma unroll
        for (int i = 0; i < 4; i++) ldst[tid + i * 256] = gsrc[tid + i * 256];
    }
    __syncthreads();

    {
        int j = tid & 127;
        int chalf = tid >> 7;
        float acc[32];
        float b = bo0[j];
#pragma unroll
        for (int c = 0; c < 32; c++) acc[c] = b;
        for (int k = 0; k < 64; k += 4) {
            float w0 = wo0[(k + 0) * 128 + j];
            float w1 = wo0[(k + 1) * 128 + j];
            float w2 = wo0[(k + 2) * 128 + j];
            float w3 = wo0[(k + 3) * 128 + j];
#pragma unroll
            for (int c = 0; c < 32; c++) {
                const float4 av = *(const float4*)&s_agg[(chalf * 32 + c) * 64 + k];
                acc[c] = fmaf(av.x, w0, acc[c]);
                acc[c] = fmaf(av.y, w1, acc[c]);
                acc[c] = fmaf(av.z, w2, acc[c]);
                acc[c] = fmaf(av.w, w3, acc[c]);
            }
        }
#pragma unroll
        for (int c = 0; c < 32; c++)
            s_mid[(chalf * 32 + c) * 128 + j] = fmaxf(acc[c], 0.f);
    }
    __syncthreads();

    {
        int m = tid;
        float acc[64];
        float b = bo1[m];
#pragma unroll
        for (int c = 0; c < 64; c++) acc[c] = b;
        for (int j = 0; j < 128; j += 4) {
            float w0 = wo1[(j + 0) * 256 + m];
            float w1 = wo1[(j + 1) * 256 + m];
            float w2 = wo1[(j + 2) * 256 + m];
            float w3 = wo1[(j + 3) * 256 + m];
#pragma unroll
            for (int c = 0; c < 64; c++) {
                const float4 mv = *(const float4*)&s_mid[c * 128 + j];
                acc[c] = fmaf(mv.x, w0, acc[c]);
                acc[c] = fmaf(mv.y, w1, acc[c]);
                acc[c] = fmaf(mv.z, w2, acc[c]);
                acc[c] = fmaf(mv.w, w3, acc[c]);
            }
        }
#pragma unroll
        for (int c = 0; c < 64; c++)
            out[(size_t)(c0 + c) * 256 + m] = fmaxf(acc[c], 0.f);
    }
}

extern "C" void kernel_launch(void* const* d_in, const int* in_sizes, int n_in,
                              void* d_out, int out_size, void* d_ws, size_t ws_size,
                              hipStream_t stream)
{
    const float* pf      = (const float*)d_in[0];
    const int*   labels  = (const int*)d_in[1];
    const float* centers = (const float*)d_in[2];
    const float* points  = (const float*)d_in[3];
    const float* we0 = (const float*)d_in[4];
    const float* be0 = (const float*)d_in[5];
    const float* we1 = (const float*)d_in[6];
    const float* be1 = (const float*)d_in[7];
    const float* we2 = (const float*)d_in[8];
    const float* be2 = (const float*)d_in[9];
    const float* we3 = (const float*)d_in[10];
    const float* be3 = (const float*)d_in[11];
    const float* wa0 = (const float*)d_in[12];
    const float* ba0 = (const float*)d_in[13];
    const float* wa1 = (const float*)d_in[14];
    const float* ba1 = (const float*)d_in[15];
    const float* wo0 = (const float*)d_in[16];
    const float* bo0 = (const float*)d_in[17];
    const float* wo1 = (const float*)d_in[18];
    const float* bo1 = (const float*)d_in[19];
    float* out = (float*)d_out;

    int n = in_sizes[0] / 8;        // N points (2,000,000)
    int C = in_sizes[2] / 3;        // clusters (65,536)

    // workspace layout: agg first (16B-aligned for float4), then int arrays
    float* agg  = (float*)d_ws;                 // C*64 floats
    int* counts = (int*)(agg + (size_t)C * 64); // C
    int* cursor = counts + C;                   // C
    int* off    = cursor + C;                   // C+1
    int* sorted = off + C + 1;                  // n

    hipMemsetAsync(counts, 0, (size_t)C * sizeof(int), stream);

    int pblocks = (n + TPB - 1) / TPB;
    hist_kernel<<<pblocks, TPB, 0, stream>>>(labels, counts, n);
    scan_kernel<<<1, 1024, 0, stream>>>(counts, off, cursor, C);
    scatter_kernel<<<pblocks, TPB, 0, stream>>>(labels, cursor, sorted, n);

    point_compute_kernel<<<C / NC, TPB, 0, stream>>>(
        pf, labels, centers, points,
        we0, be0, we1, be1, we2, be2, we3, be3,
        wa0, ba0, wa1, ba1, off, sorted, agg);

    out_mlp_kernel<<<C / 64, TPB, 0, stream>>>(agg, wo0, bo0, wo1, bo1, out);
}

// Round 3
// 1151.043 us; speedup vs baseline: 5.9848x; 3.8975x over previous
//
#include <hip/hip_runtime.h>
#include <hip/hip_bf16.h>
#include <math.h>
#include <stdint.h>

#define TPB 256

// ---------------------------------------------------------------------------
// Sort stage 1: histogram of labels
// ---------------------------------------------------------------------------
__global__ __launch_bounds__(TPB) void hist_kernel(
    const int* __restrict__ labels, int* __restrict__ counts, int n)
{
    int i = blockIdx.x * TPB + threadIdx.x;
    if (i < n) atomicAdd(&counts[labels[i]], 1);
}

// ---------------------------------------------------------------------------
// Sort stage 2: exclusive prefix sum over C bins (single block, 1024 thr)
// ---------------------------------------------------------------------------
__global__ __launch_bounds__(1024) void scan_kernel(
    const int* __restrict__ counts, int* __restrict__ off,
    int* __restrict__ cursor, int C)
{
    __shared__ int part[1024];
    int t = threadIdx.x;
    int per = C / 1024;
    int b0 = t * per;
    int s = 0;
    for (int k = 0; k < per; k++) s += counts[b0 + k];
    part[t] = s;
    __syncthreads();
    for (int d = 1; d < 1024; d <<= 1) {
        int v = 0;
        if (t >= d) v = part[t - d];
        __syncthreads();
        if (t >= d) part[t] += v;
        __syncthreads();
    }
    int run = part[t] - s;
    for (int k = 0; k < per; k++) {
        off[b0 + k] = run;
        cursor[b0 + k] = run;
        run += counts[b0 + k];
    }
    if (t == 1023) off[C] = run;
}

// ---------------------------------------------------------------------------
// Sort stage 3: scatter point ids into cluster-sorted order
// ---------------------------------------------------------------------------
__global__ __launch_bounds__(TPB) void scatter_kernel(
    const int* __restrict__ labels, int* __restrict__ cursor,
    int* __restrict__ sorted, int n)
{
    int i = blockIdx.x * TPB + threadIdx.x;
    if (i < n) {
        int pos = atomicAdd(&cursor[labels[i]], 1);
        sorted[pos] = i;
    }
}

// ---------------------------------------------------------------------------
// Stage 1: per-point MLP (round-1 structure: 1 point/thread, coalesced,
// no LDS, no atomics). Writes gated 64-vector as bf16 rows to tbuf[N][64].
// ---------------------------------------------------------------------------
__global__ __launch_bounds__(TPB) void point_mlp_kernel(
    const float* __restrict__ pf, const int* __restrict__ labels,
    const float* __restrict__ centers, const float* __restrict__ points,
    const float* __restrict__ we0, const float* __restrict__ be0,
    const float* __restrict__ we1, const float* __restrict__ be1,
    const float* __restrict__ we2, const float* __restrict__ be2,
    const float* __restrict__ we3, const float* __restrict__ be3,
    const float* __restrict__ wa0, const float* __restrict__ ba0,
    const float* __restrict__ wa1, const float* __restrict__ ba1,
    unsigned short* __restrict__ tbuf, int n)
{
    int i = blockIdx.x * TPB + threadIdx.x;
    if (i >= n) return;

    float x[11];
    const float4* pf4 = (const float4*)pf;
    float4 p0 = pf4[(size_t)i * 2 + 0];
    float4 p1 = pf4[(size_t)i * 2 + 1];
    x[0] = p0.x; x[1] = p0.y; x[2] = p0.z; x[3] = p0.w;
    x[4] = p1.x; x[5] = p1.y; x[6] = p1.z; x[7] = p1.w;

    int lbl = labels[i];
    x[8]  = centers[lbl * 3 + 0] - points[(size_t)i * 3 + 0];
    x[9]  = centers[lbl * 3 + 1] - points[(size_t)i * 3 + 1];
    x[10] = centers[lbl * 3 + 2] - points[(size_t)i * 3 + 2];

    // attention MLP: 11 -> 64 relu -> 1 sigmoid
    float s = ba1[0];
#pragma unroll
    for (int j = 0; j < 64; j++) {
        float aj = ba0[j];
#pragma unroll
        for (int k = 0; k < 11; k++) aj = fmaf(x[k], wa0[k * 64 + j], aj);
        aj = fmaxf(aj, 0.f);
        s = fmaf(aj, wa1[j], s);
    }
    float gate = 1.f / (1.f + __expf(-s));

    // edge MLP: 11 -> 8 -> 16 -> 32
    float h1[8];
#pragma unroll
    for (int j = 0; j < 8; j++) {
        float v = be0[j];
#pragma unroll
        for (int k = 0; k < 11; k++) v = fmaf(x[k], we0[k * 8 + j], v);
        h1[j] = fmaxf(v, 0.f);
    }
    float h2[16];
#pragma unroll
    for (int j = 0; j < 16; j++) {
        float v = be1[j];
#pragma unroll
        for (int k = 0; k < 8; k++) v = fmaf(h1[k], we1[k * 16 + j], v);
        h2[j] = fmaxf(v, 0.f);
    }
    float h3[32];
#pragma unroll
    for (int j = 0; j < 32; j++) {
        float v = be2[j];
#pragma unroll
        for (int k = 0; k < 16; k++) v = fmaf(h2[k], we2[k * 32 + j], v);
        h3[j] = fmaxf(v, 0.f);
    }

    // final layer 32 -> 64, relu, gate, pack bf16, store 16B chunks
    uint4* dst = (uint4*)(tbuf + (size_t)i * 64);
#pragma unroll
    for (int g = 0; g < 8; g++) {       // 8 features per group
        unsigned int w[4];
#pragma unroll
        for (int q = 0; q < 4; q++) {   // 2 features per uint
            unsigned int packed = 0;
#pragma unroll
            for (int h = 0; h < 2; h++) {
                int j = g * 8 + q * 2 + h;
                float v = be3[j];
#pragma unroll
                for (int k = 0; k < 32; k++) v = fmaf(h3[k], we3[k * 64 + j], v);
                v = fmaxf(v, 0.f) * gate;
                __hip_bfloat16 b = __float2bfloat16(v);
                unsigned short us = *(unsigned short*)&b;
                packed |= ((unsigned int)us) << (16 * h);
            }
            w[q] = packed;
        }
        dst[g] = make_uint4(w[0], w[1], w[2], w[3]);
    }
}

// ---------------------------------------------------------------------------
// Stage 2: fused aggregation + output MLP. Block owns 64 clusters.
// Phase A: lane j of each wave accumulates feature j across the cluster's
// sorted rows (one coalesced 128B row-load per point). Phase B/C: out MLP.
// ---------------------------------------------------------------------------
__global__ __launch_bounds__(TPB) void agg_outmlp_kernel(
    const unsigned short* __restrict__ tbuf,
    const int* __restrict__ off, const int* __restrict__ sorted,
    const float* __restrict__ wo0, const float* __restrict__ bo0,
    const float* __restrict__ wo1, const float* __restrict__ bo1,
    float* __restrict__ out)
{
    __shared__ float s_agg[64 * 64];    // 16 KB
    __shared__ float s_mid[64 * 128];   // 32 KB
    int tid = threadIdx.x;
    int c0 = blockIdx.x * 64;

    // phase A: aggregate. wave w (= tid>>6) handles clusters [w*16, w*16+16)
    {
        int j  = tid & 63;   // feature owned by this lane
        int cg = tid >> 6;   // cluster group
        for (int lc = cg * 16; lc < cg * 16 + 16; lc++) {
            int pb = off[c0 + lc];
            int pe = off[c0 + lc + 1];
            float acc = 0.f;
            int p = pb;
            for (; p + 4 <= pe; p += 4) {
                int r0 = sorted[p + 0], r1 = sorted[p + 1];
                int r2 = sorted[p + 2], r3 = sorted[p + 3];
                unsigned int u0 = tbuf[(size_t)r0 * 64 + j];
                unsigned int u1 = tbuf[(size_t)r1 * 64 + j];
                unsigned int u2 = tbuf[(size_t)r2 * 64 + j];
                unsigned int u3 = tbuf[(size_t)r3 * 64 + j];
                u0 <<= 16; u1 <<= 16; u2 <<= 16; u3 <<= 16;
                acc += *(float*)&u0 + *(float*)&u1 + *(float*)&u2 + *(float*)&u3;
            }
            for (; p < pe; p++) {
                unsigned int u = tbuf[(size_t)sorted[p] * 64 + j];
                u <<= 16;
                acc += *(float*)&u;
            }
            s_agg[lc * 64 + j] = acc;
        }
    }
    __syncthreads();

    // phase B: mid[64][128] = relu(agg @ wo0 + bo0)
    {
        int j = tid & 127;
        int chalf = tid >> 7;
        float acc[32];
        float b = bo0[j];
#pragma unroll
        for (int c = 0; c < 32; c++) acc[c] = b;
        for (int k = 0; k < 64; k += 4) {
            float w0 = wo0[(k + 0) * 128 + j];
            float w1 = wo0[(k + 1) * 128 + j];
            float w2 = wo0[(k + 2) * 128 + j];
            float w3 = wo0[(k + 3) * 128 + j];
#pragma unroll
            for (int c = 0; c < 32; c++) {
                const float4 av = *(const float4*)&s_agg[(chalf * 32 + c) * 64 + k];
                acc[c] = fmaf(av.x, w0, acc[c]);
                acc[c] = fmaf(av.y, w1, acc[c]);
                acc[c] = fmaf(av.z, w2, acc[c]);
                acc[c] = fmaf(av.w, w3, acc[c]);
            }
        }
#pragma unroll
        for (int c = 0; c < 32; c++)
            s_mid[(chalf * 32 + c) * 128 + j] = fmaxf(acc[c], 0.f);
    }
    __syncthreads();

    // phase C: out[64][256] = relu(mid @ wo1 + bo1)
    {
        int m = tid;
        float acc[64];
        float b = bo1[m];
#pragma unroll
        for (int c = 0; c < 64; c++) acc[c] = b;
        for (int j = 0; j < 128; j += 4) {
            float w0 = wo1[(j + 0) * 256 + m];
            float w1 = wo1[(j + 1) * 256 + m];
            float w2 = wo1[(j + 2) * 256 + m];
            float w3 = wo1[(j + 3) * 256 + m];
#pragma unroll
            for (int c = 0; c < 64; c++) {
                const float4 mv = *(const float4*)&s_mid[c * 128 + j];
                acc[c] = fmaf(mv.x, w0, acc[c]);
                acc[c] = fmaf(mv.y, w1, acc[c]);
                acc[c] = fmaf(mv.z, w2, acc[c]);
                acc[c] = fmaf(mv.w, w3, acc[c]);
            }
        }
#pragma unroll
        for (int c = 0; c < 64; c++)
            out[(size_t)(c0 + c) * 256 + m] = fmaxf(acc[c], 0.f);
    }
}

extern "C" void kernel_launch(void* const* d_in, const int* in_sizes, int n_in,
                              void* d_out, int out_size, void* d_ws, size_t ws_size,
                              hipStream_t stream)
{
    const float* pf      = (const float*)d_in[0];
    const int*   labels  = (const int*)d_in[1];
    const float* centers = (const float*)d_in[2];
    const float* points  = (const float*)d_in[3];
    const float* we0 = (const float*)d_in[4];
    const float* be0 = (const float*)d_in[5];
    const float* we1 = (const float*)d_in[6];
    const float* be1 = (const float*)d_in[7];
    const float* we2 = (const float*)d_in[8];
    const float* be2 = (const float*)d_in[9];
    const float* we3 = (const float*)d_in[10];
    const float* be3 = (const float*)d_in[11];
    const float* wa0 = (const float*)d_in[12];
    const float* ba0 = (const float*)d_in[13];
    const float* wa1 = (const float*)d_in[14];
    const float* ba1 = (const float*)d_in[15];
    const float* wo0 = (const float*)d_in[16];
    const float* bo0 = (const float*)d_in[17];
    const float* wo1 = (const float*)d_in[18];
    const float* bo1 = (const float*)d_in[19];
    float* out = (float*)d_out;

    int n = in_sizes[0] / 8;        // N points (2,000,000)
    int C = in_sizes[2] / 3;        // clusters (65,536)

    // workspace layout
    int* counts = (int*)d_ws;                   // C
    int* cursor = counts + C;                   // C
    int* off    = cursor + C;                   // C+1
    int* sorted = off + C + 1;                  // n
    uintptr_t tb = ((uintptr_t)(sorted + n) + 255) & ~(uintptr_t)255;
    unsigned short* tbuf = (unsigned short*)tb; // n x 64 bf16 (256 MB)

    hipMemsetAsync(counts, 0, (size_t)C * sizeof(int), stream);

    int pblocks = (n + TPB - 1) / TPB;
    hist_kernel<<<pblocks, TPB, 0, stream>>>(labels, counts, n);
    scan_kernel<<<1, 1024, 0, stream>>>(counts, off, cursor, C);
    scatter_kernel<<<pblocks, TPB, 0, stream>>>(labels, cursor, sorted, n);

    point_mlp_kernel<<<pblocks, TPB, 0, stream>>>(
        pf, labels, centers, points,
        we0, be0, we1, be1, we2, be2, we3, be3,
        wa0, ba0, wa1, ba1, tbuf, n);

    agg_outmlp_kernel<<<C / 64, TPB, 0, stream>>>(
        tbuf, off, sorted, wo0, bo0, wo1, bo1, out);
}

// Round 4
// 750.979 us; speedup vs baseline: 9.1731x; 1.5327x over previous
//
#include <hip/hip_runtime.h>
#include <hip/hip_bf16.h>
#include <math.h>
#include <stdint.h>

#define TPB 256
#define NCB 32   // clusters per agg block

// ---------------------------------------------------------------------------
// Sort stage 1: histogram of labels
// ---------------------------------------------------------------------------
__global__ __launch_bounds__(TPB) void hist_kernel(
    const int* __restrict__ labels, int* __restrict__ counts, int n)
{
    int i = blockIdx.x * TPB + threadIdx.x;
    if (i < n) atomicAdd(&counts[labels[i]], 1);
}

// ---------------------------------------------------------------------------
// Sort stage 2: exclusive prefix sum over C bins (single block, 1024 thr)
// ---------------------------------------------------------------------------
__global__ __launch_bounds__(1024) void scan_kernel(
    const int* __restrict__ counts, int* __restrict__ off,
    int* __restrict__ cursor, int C)
{
    __shared__ int part[1024];
    int t = threadIdx.x;
    int per = C / 1024;
    int b0 = t * per;
    int s = 0;
    for (int k = 0; k < per; k++) s += counts[b0 + k];
    part[t] = s;
    __syncthreads();
    for (int d = 1; d < 1024; d <<= 1) {
        int v = 0;
        if (t >= d) v = part[t - d];
        __syncthreads();
        if (t >= d) part[t] += v;
        __syncthreads();
    }
    int run = part[t] - s;
    for (int k = 0; k < per; k++) {
        off[b0 + k] = run;
        cursor[b0 + k] = run;
        run += counts[b0 + k];
    }
    if (t == 1023) off[C] = run;
}

// ---------------------------------------------------------------------------
// Stage 1: per-point MLP, one point/thread, coalesced input reads.
// Claims its sorted slot via cursor atomic and writes the gated bf16
// 64-vector row DIRECTLY at the sorted position: scattered stores, but a
// row is 128B = exactly one cacheline -> no write amplification, and
// stores don't stall the wave (unlike the old gather-read in stage 2).
// ---------------------------------------------------------------------------
__global__ __launch_bounds__(TPB) void point_mlp_kernel(
    const float* __restrict__ pf, const int* __restrict__ labels,
    const float* __restrict__ centers, const float* __restrict__ points,
    const float* __restrict__ we0, const float* __restrict__ be0,
    const float* __restrict__ we1, const float* __restrict__ be1,
    const float* __restrict__ we2, const float* __restrict__ be2,
    const float* __restrict__ we3, const float* __restrict__ be3,
    const float* __restrict__ wa0, const float* __restrict__ ba0,
    const float* __restrict__ wa1, const float* __restrict__ ba1,
    int* __restrict__ cursor, unsigned short* __restrict__ tsort, int n)
{
    int i = blockIdx.x * TPB + threadIdx.x;
    if (i >= n) return;

    float x[11];
    const float4* pf4 = (const float4*)pf;
    float4 p0 = pf4[(size_t)i * 2 + 0];
    float4 p1 = pf4[(size_t)i * 2 + 1];
    x[0] = p0.x; x[1] = p0.y; x[2] = p0.z; x[3] = p0.w;
    x[4] = p1.x; x[5] = p1.y; x[6] = p1.z; x[7] = p1.w;

    int lbl = labels[i];
    x[8]  = centers[lbl * 3 + 0] - points[(size_t)i * 3 + 0];
    x[9]  = centers[lbl * 3 + 1] - points[(size_t)i * 3 + 1];
    x[10] = centers[lbl * 3 + 2] - points[(size_t)i * 3 + 2];

    // claim sorted slot early; latency overlaps the MLP compute below
    int pos = atomicAdd(&cursor[lbl], 1);

    // attention MLP: 11 -> 64 relu -> 1 sigmoid
    float s = ba1[0];
#pragma unroll
    for (int j = 0; j < 64; j++) {
        float aj = ba0[j];
#pragma unroll
        for (int k = 0; k < 11; k++) aj = fmaf(x[k], wa0[k * 64 + j], aj);
        aj = fmaxf(aj, 0.f);
        s = fmaf(aj, wa1[j], s);
    }
    float gate = 1.f / (1.f + __expf(-s));

    // edge MLP: 11 -> 8 -> 16 -> 32
    float h1[8];
#pragma unroll
    for (int j = 0; j < 8; j++) {
        float v = be0[j];
#pragma unroll
        for (int k = 0; k < 11; k++) v = fmaf(x[k], we0[k * 8 + j], v);
        h1[j] = fmaxf(v, 0.f);
    }
    float h2[16];
#pragma unroll
    for (int j = 0; j < 16; j++) {
        float v = be1[j];
#pragma unroll
        for (int k = 0; k < 8; k++) v = fmaf(h1[k], we1[k * 16 + j], v);
        h2[j] = fmaxf(v, 0.f);
    }
    float h3[32];
#pragma unroll
    for (int j = 0; j < 32; j++) {
        float v = be2[j];
#pragma unroll
        for (int k = 0; k < 16; k++) v = fmaf(h2[k], we2[k * 32 + j], v);
        h3[j] = fmaxf(v, 0.f);
    }

    // final layer 32 -> 64, relu, gate, pack bf16, store row at sorted pos
    uint4* dst = (uint4*)(tsort + (size_t)pos * 64);
#pragma unroll
    for (int g = 0; g < 8; g++) {
        unsigned int w[4];
#pragma unroll
        for (int q = 0; q < 4; q++) {
            unsigned int packed = 0;
#pragma unroll
            for (int h = 0; h < 2; h++) {
                int j = g * 8 + q * 2 + h;
                float v = be3[j];
#pragma unroll
                for (int k = 0; k < 32; k++) v = fmaf(h3[k], we3[k * 64 + j], v);
                v = fmaxf(v, 0.f) * gate;
                __hip_bfloat16 b = __float2bfloat16(v);
                unsigned short us = *(unsigned short*)&b;
                packed |= ((unsigned int)us) << (16 * h);
            }
            w[q] = packed;
        }
        dst[g] = make_uint4(w[0], w[1], w[2], w[3]);
    }
}

// ---------------------------------------------------------------------------
// Stage 2: aggregation (fully coalesced streaming over tsort) + output MLP.
// Block owns NCB=32 clusters; wave w handles 8 of them. A wave-load of
// uint covers 2 rows x 64 features (256B contiguous). Half-wave partial
// sums are combined with __shfl at each cluster end.
// ---------------------------------------------------------------------------
__global__ __launch_bounds__(TPB) void agg_outmlp_kernel(
    const unsigned short* __restrict__ tsort,
    const int* __restrict__ off,
    const float* __restrict__ wo0, const float* __restrict__ bo0,
    const float* __restrict__ wo1, const float* __restrict__ bo1,
    float* __restrict__ out)
{
    __shared__ float s_agg[NCB * 64];    // 8 KB
    __shared__ float s_mid[NCB * 128];   // 16 KB
    int tid = threadIdx.x;
    int c0 = blockIdx.x * NCB;
    const unsigned int* t32 = (const unsigned int*)tsort;

    // phase A: aggregate
    {
        int l = tid & 63;
        int w = tid >> 6;
#define BF_LO(u) (__uint_as_float((u) << 16))
#define BF_HI(u) (__uint_as_float((u) & 0xffff0000u))
        for (int lc = w * 8; lc < w * 8 + 8; lc++) {
            int rb = off[c0 + lc];
            int re = off[c0 + lc + 1];
            float a0 = 0.f, a1 = 0.f;
            int r = rb;
            for (; r + 8 <= re; r += 8) {
                unsigned int u0 = t32[(size_t)(r + 0) * 32 + l];
                unsigned int u1 = t32[(size_t)(r + 2) * 32 + l];
                unsigned int u2 = t32[(size_t)(r + 4) * 32 + l];
                unsigned int u3 = t32[(size_t)(r + 6) * 32 + l];
                a0 += BF_LO(u0) + BF_LO(u1) + BF_LO(u2) + BF_LO(u3);
                a1 += BF_HI(u0) + BF_HI(u1) + BF_HI(u2) + BF_HI(u3);
            }
            for (; r + 2 <= re; r += 2) {
                unsigned int u = t32[(size_t)r * 32 + l];
                a0 += BF_LO(u);
                a1 += BF_HI(u);
            }
            if (r < re && l < 32) {          // odd tail row: lower half only
                unsigned int u = t32[(size_t)r * 32 + l];
                a0 += BF_LO(u);
                a1 += BF_HI(u);
            }
            // combine the two half-wave partials
            float b0 = __shfl(a0, (l + 32) & 63, 64);
            float b1 = __shfl(a1, (l + 32) & 63, 64);
            if (l < 32) {
                float2 v;
                v.x = a0 + b0;   // feature 2l
                v.y = a1 + b1;   // feature 2l+1
                *(float2*)&s_agg[lc * 64 + 2 * l] = v;
            }
        }
#undef BF_LO
#undef BF_HI
    }
    __syncthreads();

    // phase B: mid[NCB][128] = relu(agg @ wo0 + bo0)
    {
        int j = tid & 127;
        int g = tid >> 7;            // 0/1: which 16-cluster half
        float acc[16];
        float b = bo0[j];
#pragma unroll
        for (int c = 0; c < 16; c++) acc[c] = b;
        for (int k = 0; k < 64; k += 4) {
            float w0 = wo0[(k + 0) * 128 + j];
            float w1 = wo0[(k + 1) * 128 + j];
            float w2 = wo0[(k + 2) * 128 + j];
            float w3 = wo0[(k + 3) * 128 + j];
#pragma unroll
            for (int c = 0; c < 16; c++) {
                const float4 av = *(const float4*)&s_agg[(g * 16 + c) * 64 + k];
                acc[c] = fmaf(av.x, w0, acc[c]);
                acc[c] = fmaf(av.y, w1, acc[c]);
                acc[c] = fmaf(av.z, w2, acc[c]);
                acc[c] = fmaf(av.w, w3, acc[c]);
            }
        }
#pragma unroll
        for (int c = 0; c < 16; c++)
            s_mid[(g * 16 + c) * 128 + j] = fmaxf(acc[c], 0.f);
    }
    __syncthreads();

    // phase C: out[NCB][256] = relu(mid @ wo1 + bo1)
    {
        int m = tid;
        float acc[NCB];
        float b = bo1[m];
#pragma unroll
        for (int c = 0; c < NCB; c++) acc[c] = b;
        for (int j = 0; j < 128; j += 4) {
            float w0 = wo1[(j + 0) * 256 + m];
            float w1 = wo1[(j + 1) * 256 + m];
            float w2 = wo1[(j + 2) * 256 + m];
            float w3 = wo1[(j + 3) * 256 + m];
#pragma unroll
            for (int c = 0; c < NCB; c++) {
                const float4 mv = *(const float4*)&s_mid[c * 128 + j];
                acc[c] = fmaf(mv.x, w0, acc[c]);
                acc[c] = fmaf(mv.y, w1, acc[c]);
                acc[c] = fmaf(mv.z, w2, acc[c]);
                acc[c] = fmaf(mv.w, w3, acc[c]);
            }
        }
#pragma unroll
        for (int c = 0; c < NCB; c++)
            out[(size_t)(c0 + c) * 256 + m] = fmaxf(acc[c], 0.f);
    }
}

extern "C" void kernel_launch(void* const* d_in, const int* in_sizes, int n_in,
                              void* d_out, int out_size, void* d_ws, size_t ws_size,
                              hipStream_t stream)
{
    const float* pf      = (const float*)d_in[0];
    const int*   labels  = (const int*)d_in[1];
    const float* centers = (const float*)d_in[2];
    const float* points  = (const float*)d_in[3];
    const float* we0 = (const float*)d_in[4];
    const float* be0 = (const float*)d_in[5];
    const float* we1 = (const float*)d_in[6];
    const float* be1 = (const float*)d_in[7];
    const float* we2 = (const float*)d_in[8];
    const float* be2 = (const float*)d_in[9];
    const float* we3 = (const float*)d_in[10];
    const float* be3 = (const float*)d_in[11];
    const float* wa0 = (const float*)d_in[12];
    const float* ba0 = (const float*)d_in[13];
    const float* wa1 = (const float*)d_in[14];
    const float* ba1 = (const float*)d_in[15];
    const float* wo0 = (const float*)d_in[16];
    const float* bo0 = (const float*)d_in[17];
    const float* wo1 = (const float*)d_in[18];
    const float* bo1 = (const float*)d_in[19];
    float* out = (float*)d_out;

    int n = in_sizes[0] / 8;        // N points (2,000,000)
    int C = in_sizes[2] / 3;        // clusters (65,536)

    // workspace layout
    int* counts = (int*)d_ws;                   // C
    int* cursor = counts + C;                   // C
    int* off    = cursor + C;                   // C+1
    uintptr_t tb = ((uintptr_t)(off + C + 1) + 255) & ~(uintptr_t)255;
    unsigned short* tsort = (unsigned short*)tb; // n x 64 bf16, cluster-sorted

    hipMemsetAsync(counts, 0, (size_t)C * sizeof(int), stream);

    int pblocks = (n + TPB - 1) / TPB;
    hist_kernel<<<pblocks, TPB, 0, stream>>>(labels, counts, n);
    scan_kernel<<<1, 1024, 0, stream>>>(counts, off, cursor, C);

    point_mlp_kernel<<<pblocks, TPB, 0, stream>>>(
        pf, labels, centers, points,
        we0, be0, we1, be1, we2, be2, we3, be3,
        wa0, ba0, wa1, ba1, cursor, tsort, n);

    agg_outmlp_kernel<<<C / NCB, TPB, 0, stream>>>(
        tsort, off, wo0, bo0, wo1, bo1, out);
}